// Round 12
// baseline (429.713 us; speedup 1.0000x reference)
//
#include <hip/hip_runtime.h>

// LSTM (B=2048, T=1024, I=8, H=64) + sigmoid(FC), bf16 MFMA, in-register
// activations, duplicate-column split, 2 blocks/CU — ANTI-PHASE + WEIGHT-
// FOLDED EXP SCALES.
//
// Machine model (locked r0-r11): per step each block runs an MFMA phase
// (~440cy pipe) then a VALU act phase (~480cy). A ONE-TIME s_sleep(7)
// stagger for half the blocks seeds MFMA/VALU anti-phase between the two
// co-resident blocks; verified r8/r11: MfmaUtil+VALUBusy = 112.5% > 100%,
// 393 -> 389us. DO NOT REMOVE THE STAGGER.
//
// THE LOCK IS FRAGILE TO PHASE-STRUCTURE EDITS (measured):
//   r9  (x-MFMAs moved mid-step): sum 90%, 462us.
//   r10 (fx ds_read hoisted into act phase): sum 99%, 425us.
// => memory ops, MFMA order (x->h0->h1), barrier placement are r8-identical.
//
// r12: constants-only VALU cut. All exp input scales are folded into the
// weights at init: gate rows i,f,o scaled by -log2e (sigmoid becomes
// rcp(1+exp2(y)) with NO input mul), gate-g rows by +2*log2e. The cell
// state is tracked pre-scaled (c' = 2*log2e*c) by emitting
// g' = 2log2e*tanh(g) via the same fma that computed 1-2r, so tanh(c) =
// 1-2*rcp(exp2(c')+1) also needs no mul. Removes 5 v_mul from the serial
// act chain per cell; act phase structure otherwise byte-identical.
// exp2 emitted as raw v_exp_f32 (builtin w/ asm fallback — NOT exp2f,
// which lowers to slow ocml per r2's +22% VALU regression).
//
// Verified keeps: HP=80 (r0's 40 aliased h rows — correctness), manual f2bf
// init, v_cvt_pk_bf16_f32 h-store, plain __syncthreads, full unroll on tt.

namespace {
constexpr int T_LEN = 1024;
constexpr int R     = 4;    // batch rows per block
constexpr int TS    = 32;   // timesteps of x per staged chunk
constexpr int HP    = 80;   // h_lds row stride in shorts (160 B, 16B-aligned)
constexpr float L2E = 1.4426950408889634f;

typedef __attribute__((ext_vector_type(8))) short  short8v;
typedef __attribute__((ext_vector_type(4))) float  float4v;
typedef unsigned short u16;
typedef unsigned long long u64;
typedef unsigned int u32;

__device__ __forceinline__ float exp2_raw(float x) {  // raw v_exp_f32
#if __has_builtin(__builtin_amdgcn_exp2f)
  return __builtin_amdgcn_exp2f(x);
#else
  float r;
  asm("v_exp_f32 %0, %1" : "=v"(r) : "v"(x));
  return r;
#endif
}
// y already scaled by -log2e: sigmoid = rcp(1 + 2^y). No input mul.
__device__ __forceinline__ float fsig_p(float y) {
  return __builtin_amdgcn_rcpf(1.f + exp2_raw(y));
}
__device__ __forceinline__ u16 f2bf(float f) {  // RNE (init-time only)
  u32 u = __float_as_uint(f);
  u32 r = ((u >> 16) & 1u) + 0x7fffu;
  return (u16)((u + r) >> 16);
}
__device__ __forceinline__ u16 cvt_bf16(float f) {  // 1 VALU op, RNE
  u32 d;
  asm("v_cvt_pk_bf16_f32 %0, %1, %2" : "=v"(d) : "v"(f), "v"(f));
  return (u16)d;
}

__global__ __launch_bounds__(256, 2) void lstm_split(
    const float* __restrict__ x,     // [B, T, 8]
    const float* __restrict__ W_ih,  // [256, 8]
    const float* __restrict__ W_hh,  // [256, 64]
    const float* __restrict__ b_ih,  // [256]
    const float* __restrict__ b_hh,  // [256]
    const float* __restrict__ fc_w,  // [64]
    const float* __restrict__ fc_b,  // [1]
    float* __restrict__ out) {       // [B]
  __shared__ __align__(16) u16   x_lds[2][TS][R][32];  // 16 KB; full K-rows
  __shared__ __align__(16) u16   h_lds[2][R][HP];      // 2.5 KB
  __shared__ __align__(16) float hf[R][64];            // final h (fp32)

  const int tid  = threadIdx.x;
  const int lane = tid & 63;
  const int wv   = tid >> 6;       // wave 0..3
  const int g4   = lane >> 4;      // MFMA k-quad / C row-quad
  const int nib  = lane & 15;      // MFMA m/n coord
  const int row  = nib & 3;        // batch row (cols 4..15 duplicate 0..3)
  const int rsel = nib >> 2;       // which acc reg this thread activates
  const int jh   = 16 * wv + 4 * g4 + rsel;  // owned h index
  const int bBase = blockIdx.x * R;

  // ---- static A fragments: wave wv holds tiles {4g+wv}, g=0..3 (i,f,g,o) ----
  // A[m=16*(4g+wv)+nib][k=8*g4+j]; frag0 k=0..31 = [W_ih(8)|bias|0...],
  // frag1 = W_hh[:,0:32], frag2 = W_hh[:,32:64].
  // EXP-SCALE FOLD: rows of gates i,f,o (g!=2) x(-log2e); gate g x(+2log2e).
  short8v a0[4], a1[4], a2[4];
  for (int g = 0; g < 4; ++g) {
    const float sc = (g == 2) ? (2.f * L2E) : (-L2E);
    const int n = 64 * g + 16 * wv + nib;  // gate row
    short8v f0, f1, f2;
    for (int j = 0; j < 8; ++j) {
      const int k = 8 * g4 + j;
      float v0 = 0.f;
      if (k < 8) v0 = W_ih[n * 8 + k];
      else if (k == 8) v0 = b_ih[n] + b_hh[n];
      f0[j] = (short)f2bf(sc * v0);
      f1[j] = (short)f2bf(sc * W_hh[n * 64 + k]);
      f2[j] = (short)f2bf(sc * W_hh[n * 64 + 32 + k]);
    }
    a0[g] = f0; a1[g] = f1; a2[g] = f2;
  }

  // ---- LDS init: h0 = 0 (both bufs); x constant channels once per buf ----
  for (int i = tid; i < 2 * R * HP; i += 256) ((u16*)h_lds)[i] = 0;
  {  // 256 threads <-> 2 bufs x 32 tt x 4 rows
    const int buf = tid >> 7, rem = tid & 127, tt = rem >> 2, rr = rem & 3;
    u16* p = &x_lds[buf][tt][rr][0];
    p[8] = 0x3f80;  // bias channel = 1.0
    for (int chn = 9; chn < 32; ++chn) p[chn] = 0;
  }

  // ---- x staging: 1 float4/thread/chunk, double-buffered ----
  float4v xr;
  const int sr = tid >> 6, sm = tid & 63;          // src row, float4 idx
  const int stt = sm >> 1, sch = (sm & 1) * 4;     // dest tt, channel
  auto stage_load = [&](int chunk) {
    const float* src = x + ((size_t)bBase + sr) * (T_LEN * 8) +
                       (size_t)chunk * (TS * 8);
    xr = *(const float4v*)&src[sm * 4];
  };
  auto stage_write = [&](int buf) {
    u32 lo, hi;
    asm("v_cvt_pk_bf16_f32 %0, %1, %2" : "=v"(lo) : "v"(xr[0]), "v"(xr[1]));
    asm("v_cvt_pk_bf16_f32 %0, %1, %2" : "=v"(hi) : "v"(xr[2]), "v"(xr[3]));
    const u64 p = ((u64)hi << 32) | (u64)lo;
    *(u64*)&x_lds[buf][stt][sr][sch] = p;
  };

  stage_load(0);
  stage_write(0);
  __syncthreads();

  // ---- ANTI-PHASE SEED: one-time ~448cy stagger for half the blocks ----
  // Parity (blockIdx ^ blockIdx>>8)&1 splits co-resident pairs under both
  // plausible mappings: (i, i+256) XCD round-robin and (2i, 2i+1).
  if (((blockIdx.x ^ (blockIdx.x >> 8)) & 1) != 0)
    __builtin_amdgcn_s_sleep(7);  // 7*64 = 448 cycles, once

  // hoisted select masks for the cndmask tree
  const bool sel1 = (rsel & 1) != 0;
  const bool sel2 = (rsel & 2) != 0;
  float c = 0.f;  // pre-scaled cell state: c' = 2*log2e * c_true

  for (int ch = 0; ch < T_LEN / TS; ++ch) {
    const int xb = ch & 1;
    const bool more = (ch < T_LEN / TS - 1);
#pragma unroll
    for (int tt = 0; tt < TS; ++tt) {
      const int t = ch * TS + tt;
      const int hb = t & 1;  // == tt & 1 (TS even); compile-time under unroll
      if (tt == 0 && more) stage_load(ch + 1);  // reg loads; drain in stage_write

      // ---- B fragments (uniform b128 reads) ----
      const short8v fx  = *(const short8v*)&x_lds[xb][tt][row][8 * g4];
      const short8v fh0 = *(const short8v*)&h_lds[hb][row][8 * g4];
      const short8v fh1 = *(const short8v*)&h_lds[hb][row][32 + 8 * g4];

      // ---- 12 MFMAs: 4 gate-quads x (x | h-lo | h-hi) ----
      float4v acc[4];
#pragma unroll
      for (int g = 0; g < 4; ++g)
        acc[g] = __builtin_amdgcn_mfma_f32_16x16x32_bf16(
            a0[g], fx, (float4v){0.f, 0.f, 0.f, 0.f}, 0, 0, 0);
#pragma unroll
      for (int g = 0; g < 4; ++g)
        acc[g] = __builtin_amdgcn_mfma_f32_16x16x32_bf16(a1[g], fh0, acc[g], 0, 0, 0);
#pragma unroll
      for (int g = 0; g < 4; ++g)
        acc[g] = __builtin_amdgcn_mfma_f32_16x16x32_bf16(a2[g], fh1, acc[g], 0, 0, 0);

      // ---- pick this thread's element (reg-select tree) and activate ----
      // gsel values arrive pre-scaled: i,f,o by -log2e; g by 2log2e.
      float gsel[4];
#pragma unroll
      for (int g = 0; g < 4; ++g) {
        const float x01 = sel1 ? acc[g][1] : acc[g][0];
        const float x23 = sel1 ? acc[g][3] : acc[g][2];
        gsel[g] = sel2 ? x23 : x01;
      }
      const float iv = fsig_p(gsel[0]);
      const float fv = fsig_p(gsel[1]);
      // g' = 2log2e*tanh(g) = fma(-4log2e, r, 2log2e): same fma as 1-2r
      const float rg = __builtin_amdgcn_rcpf(exp2_raw(gsel[2]) + 1.f);
      const float gv = __builtin_fmaf(-4.f * L2E, rg, 2.f * L2E);
      const float ov = fsig_p(gsel[3]);
      c = __builtin_fmaf(fv, c, iv * gv);  // c' = f*c' + i*g' (pre-scaled)
      // tanh(c_true) = 1 - 2*rcp(exp2(c') + 1): no input mul
      const float rc = __builtin_amdgcn_rcpf(exp2_raw(c) + 1.f);
      const float th = __builtin_fmaf(-2.f, rc, 1.f);
      const float h = ov * th;
      h_lds[hb ^ 1][row][jh] = cvt_bf16(h);
      if (t == T_LEN - 1) hf[row][jh] = h;
      if (tt == TS - 1 && more) stage_write((ch + 1) & 1);
      __syncthreads();  // one barrier per step
    }
  }

  // ---- epilogue: out[b] = sigmoid(hT . fc_w + fc_b) ----
  if (tid < R) {
    float a = fc_b[0];
#pragma unroll
    for (int k = 0; k < 64; ++k) a += hf[tid][k] * fc_w[k];
    out[bBase + tid] = fsig_p(-L2E * a);  // unscaled input: explicit mul
  }
}
}  // namespace

extern "C" void kernel_launch(void* const* d_in, const int* in_sizes, int n_in,
                              void* d_out, int out_size, void* d_ws,
                              size_t ws_size, hipStream_t stream) {
  const float* x    = (const float*)d_in[0];
  const float* W_ih = (const float*)d_in[1];
  const float* W_hh = (const float*)d_in[2];
  const float* b_ih = (const float*)d_in[3];
  const float* b_hh = (const float*)d_in[4];
  const float* fc_w = (const float*)d_in[5];
  const float* fc_b = (const float*)d_in[6];
  float* out = (float*)d_out;

  const int B = in_sizes[0] / (T_LEN * 8);  // 2048
  lstm_split<<<dim3(B / R), dim3(256), 0, stream>>>(x, W_ih, W_hh, b_ih, b_hh,
                                                    fc_w, fc_b, out);
}

// Round 13
// 419.503 us; speedup vs baseline: 1.0243x; 1.0243x over previous
//
#include <hip/hip_runtime.h>

// LSTM (B=2048, T=1024, I=8, H=64) + sigmoid(FC), bf16 MFMA, in-register
// activations, duplicate-column split, 2 blocks/CU — ANTI-PHASE + WEIGHT-
// FOLDED EXP SCALES + FUSED RECIPROCALS.
//
// Machine model (locked r0-r12): per step each block runs an MFMA phase then
// a VALU act phase. A ONE-TIME s_sleep(7) stagger for half the blocks seeds
// MFMA/VALU anti-phase between the two co-resident blocks; verified r8/r11:
// MfmaUtil+VALUBusy = 112.5% > 100%, and the equilibrium self-sustains.
// DO NOT REMOVE THE STAGGER.
//
// THE LOCK IS FRAGILE TO PHASE-STRUCTURE EDITS (measured):
//   r9  (x-MFMAs moved mid-step): sum 90%, 462us.
//   r10 (fx ds_read hoisted into act phase): sum 99%, 425us.
// SAFE CATEGORY (measured): act-internal constants-only VALU cuts —
//   r12 exp-scale fold into weights: 389->379us, lock held.
// => memory ops, MFMA order (x->h0->h1), barrier placement are r8-identical.
//
// r13: second act trim in the safe category — fuse reciprocals via
// rcp(x)*rcp(y) = rcp(x*y):
//   sig(i)*tanh(g) = (G-1) * rcp((1+I)(G+1)),  I=e^-i, G=e^{2g}
//   h = tanh(c)*sig(o) = (C-1) * rcp((C+1)(1+O)), C=e^{2c}, O=e^-o
// 10 -> 8 transcendentals per cell (5 exp + 3 rcp), +2 full-rate ops,
// same serial depth. Weights pre-scaled as in r12 (i,f,o rows x -log2e;
// g rows x +2log2e; cell state tracked pre-scaled c' = 2log2e*c).
// exp2 emitted as raw v_exp_f32 (NOT exp2f — slow ocml, r2: +22% VALU).
//
// Verified keeps: HP=80 (r0's 40 aliased h rows — correctness), manual f2bf
// init, v_cvt_pk_bf16_f32 h-store, plain __syncthreads, full unroll on tt.

namespace {
constexpr int T_LEN = 1024;
constexpr int R     = 4;    // batch rows per block
constexpr int TS    = 32;   // timesteps of x per staged chunk
constexpr int HP    = 80;   // h_lds row stride in shorts (160 B, 16B-aligned)
constexpr float L2E = 1.4426950408889634f;

typedef __attribute__((ext_vector_type(8))) short  short8v;
typedef __attribute__((ext_vector_type(4))) float  float4v;
typedef unsigned short u16;
typedef unsigned long long u64;
typedef unsigned int u32;

__device__ __forceinline__ float exp2_raw(float x) {  // raw v_exp_f32
#if __has_builtin(__builtin_amdgcn_exp2f)
  return __builtin_amdgcn_exp2f(x);
#else
  float r;
  asm("v_exp_f32 %0, %1" : "=v"(r) : "v"(x));
  return r;
#endif
}
// y already scaled by -log2e: sigmoid = rcp(1 + 2^y). No input mul.
__device__ __forceinline__ float fsig_p(float y) {
  return __builtin_amdgcn_rcpf(1.f + exp2_raw(y));
}
__device__ __forceinline__ u16 f2bf(float f) {  // RNE (init-time only)
  u32 u = __float_as_uint(f);
  u32 r = ((u >> 16) & 1u) + 0x7fffu;
  return (u16)((u + r) >> 16);
}
__device__ __forceinline__ u16 cvt_bf16(float f) {  // 1 VALU op, RNE
  u32 d;
  asm("v_cvt_pk_bf16_f32 %0, %1, %2" : "=v"(d) : "v"(f), "v"(f));
  return (u16)d;
}

__global__ __launch_bounds__(256, 2) void lstm_split(
    const float* __restrict__ x,     // [B, T, 8]
    const float* __restrict__ W_ih,  // [256, 8]
    const float* __restrict__ W_hh,  // [256, 64]
    const float* __restrict__ b_ih,  // [256]
    const float* __restrict__ b_hh,  // [256]
    const float* __restrict__ fc_w,  // [64]
    const float* __restrict__ fc_b,  // [1]
    float* __restrict__ out) {       // [B]
  __shared__ __align__(16) u16   x_lds[2][TS][R][32];  // 16 KB; full K-rows
  __shared__ __align__(16) u16   h_lds[2][R][HP];      // 2.5 KB
  __shared__ __align__(16) float hf[R][64];            // final h (fp32)

  const int tid  = threadIdx.x;
  const int lane = tid & 63;
  const int wv   = tid >> 6;       // wave 0..3
  const int g4   = lane >> 4;      // MFMA k-quad / C row-quad
  const int nib  = lane & 15;      // MFMA m/n coord
  const int row  = nib & 3;        // batch row (cols 4..15 duplicate 0..3)
  const int rsel = nib >> 2;       // which acc reg this thread activates
  const int jh   = 16 * wv + 4 * g4 + rsel;  // owned h index
  const int bBase = blockIdx.x * R;

  // ---- static A fragments: wave wv holds tiles {4g+wv}, g=0..3 (i,f,g,o) ----
  // A[m=16*(4g+wv)+nib][k=8*g4+j]; frag0 k=0..31 = [W_ih(8)|bias|0...],
  // frag1 = W_hh[:,0:32], frag2 = W_hh[:,32:64].
  // EXP-SCALE FOLD: rows of gates i,f,o (g!=2) x(-log2e); gate g x(+2log2e).
  short8v a0[4], a1[4], a2[4];
  for (int g = 0; g < 4; ++g) {
    const float sc = (g == 2) ? (2.f * L2E) : (-L2E);
    const int n = 64 * g + 16 * wv + nib;  // gate row
    short8v f0, f1, f2;
    for (int j = 0; j < 8; ++j) {
      const int k = 8 * g4 + j;
      float v0 = 0.f;
      if (k < 8) v0 = W_ih[n * 8 + k];
      else if (k == 8) v0 = b_ih[n] + b_hh[n];
      f0[j] = (short)f2bf(sc * v0);
      f1[j] = (short)f2bf(sc * W_hh[n * 64 + k]);
      f2[j] = (short)f2bf(sc * W_hh[n * 64 + 32 + k]);
    }
    a0[g] = f0; a1[g] = f1; a2[g] = f2;
  }

  // ---- LDS init: h0 = 0 (both bufs); x constant channels once per buf ----
  for (int i = tid; i < 2 * R * HP; i += 256) ((u16*)h_lds)[i] = 0;
  {  // 256 threads <-> 2 bufs x 32 tt x 4 rows
    const int buf = tid >> 7, rem = tid & 127, tt = rem >> 2, rr = rem & 3;
    u16* p = &x_lds[buf][tt][rr][0];
    p[8] = 0x3f80;  // bias channel = 1.0
    for (int chn = 9; chn < 32; ++chn) p[chn] = 0;
  }

  // ---- x staging: 1 float4/thread/chunk, double-buffered ----
  float4v xr;
  const int sr = tid >> 6, sm = tid & 63;          // src row, float4 idx
  const int stt = sm >> 1, sch = (sm & 1) * 4;     // dest tt, channel
  auto stage_load = [&](int chunk) {
    const float* src = x + ((size_t)bBase + sr) * (T_LEN * 8) +
                       (size_t)chunk * (TS * 8);
    xr = *(const float4v*)&src[sm * 4];
  };
  auto stage_write = [&](int buf) {
    u32 lo, hi;
    asm("v_cvt_pk_bf16_f32 %0, %1, %2" : "=v"(lo) : "v"(xr[0]), "v"(xr[1]));
    asm("v_cvt_pk_bf16_f32 %0, %1, %2" : "=v"(hi) : "v"(xr[2]), "v"(xr[3]));
    const u64 p = ((u64)hi << 32) | (u64)lo;
    *(u64*)&x_lds[buf][stt][sr][sch] = p;
  };

  stage_load(0);
  stage_write(0);
  __syncthreads();

  // ---- ANTI-PHASE SEED: one-time ~448cy stagger for half the blocks ----
  // Parity (blockIdx ^ blockIdx>>8)&1 splits co-resident pairs under both
  // plausible mappings: (i, i+256) XCD round-robin and (2i, 2i+1).
  if (((blockIdx.x ^ (blockIdx.x >> 8)) & 1) != 0)
    __builtin_amdgcn_s_sleep(7);  // 7*64 = 448 cycles, once

  // hoisted select masks for the cndmask tree
  const bool sel1 = (rsel & 1) != 0;
  const bool sel2 = (rsel & 2) != 0;
  float c = 0.f;  // pre-scaled cell state: c' = 2*log2e * c_true

  for (int ch = 0; ch < T_LEN / TS; ++ch) {
    const int xb = ch & 1;
    const bool more = (ch < T_LEN / TS - 1);
#pragma unroll
    for (int tt = 0; tt < TS; ++tt) {
      const int t = ch * TS + tt;
      const int hb = t & 1;  // == tt & 1 (TS even); compile-time under unroll
      if (tt == 0 && more) stage_load(ch + 1);  // reg loads; drain in stage_write

      // ---- B fragments (uniform b128 reads) ----
      const short8v fx  = *(const short8v*)&x_lds[xb][tt][row][8 * g4];
      const short8v fh0 = *(const short8v*)&h_lds[hb][row][8 * g4];
      const short8v fh1 = *(const short8v*)&h_lds[hb][row][32 + 8 * g4];

      // ---- 12 MFMAs: 4 gate-quads x (x | h-lo | h-hi) ----
      float4v acc[4];
#pragma unroll
      for (int g = 0; g < 4; ++g)
        acc[g] = __builtin_amdgcn_mfma_f32_16x16x32_bf16(
            a0[g], fx, (float4v){0.f, 0.f, 0.f, 0.f}, 0, 0, 0);
#pragma unroll
      for (int g = 0; g < 4; ++g)
        acc[g] = __builtin_amdgcn_mfma_f32_16x16x32_bf16(a1[g], fh0, acc[g], 0, 0, 0);
#pragma unroll
      for (int g = 0; g < 4; ++g)
        acc[g] = __builtin_amdgcn_mfma_f32_16x16x32_bf16(a2[g], fh1, acc[g], 0, 0, 0);

      // ---- pick this thread's element (reg-select tree) and activate ----
      // gsel arrives pre-scaled: i,f,o by -log2e; g by 2log2e.
      float gsel[4];
#pragma unroll
      for (int g = 0; g < 4; ++g) {
        const float x01 = sel1 ? acc[g][1] : acc[g][0];
        const float x23 = sel1 ? acc[g][3] : acc[g][2];
        gsel[g] = sel2 ? x23 : x01;
      }
      // I = e^-i, F = e^-f, G = e^{2g}, O = e^-o (scales folded in weights)
      const float I = exp2_raw(gsel[0]);
      const float F = exp2_raw(gsel[1]);
      const float G = exp2_raw(gsel[2]);
      const float O = exp2_raw(gsel[3]);
      // c' = sig(f)*c' + 2log2e*sig(i)*tanh(g)
      //    = rcp(1+F)*c' + [2log2e*(G-1)] * rcp((1+I)*(G+1))   (fused rcp)
      const float s   = __builtin_fmaf(2.f * L2E, G, -2.f * L2E);  // 2L2E(G-1)
      const float dIG = (1.f + I) * (G + 1.f);
      const float t2  = s * __builtin_amdgcn_rcpf(dIG);
      c = __builtin_fmaf(__builtin_amdgcn_rcpf(1.f + F), c, t2);
      // h = tanh(c)*sig(o) = (C-1) * rcp((C+1)*(1+O)), C = exp2(c') = e^{2c}
      const float C   = exp2_raw(c);
      const float dCO = (C + 1.f) * (1.f + O);
      const float h   = (C - 1.f) * __builtin_amdgcn_rcpf(dCO);
      h_lds[hb ^ 1][row][jh] = cvt_bf16(h);
      if (t == T_LEN - 1) hf[row][jh] = h;
      if (tt == TS - 1 && more) stage_write((ch + 1) & 1);
      __syncthreads();  // one barrier per step
    }
  }

  // ---- epilogue: out[b] = sigmoid(hT . fc_w + fc_b) ----
  if (tid < R) {
    float a = fc_b[0];
#pragma unroll
    for (int k = 0; k < 64; ++k) a += hf[tid][k] * fc_w[k];
    out[bBase + tid] = fsig_p(-L2E * a);  // unscaled input: explicit mul
  }
}
}  // namespace

extern "C" void kernel_launch(void* const* d_in, const int* in_sizes, int n_in,
                              void* d_out, int out_size, void* d_ws,
                              size_t ws_size, hipStream_t stream) {
  const float* x    = (const float*)d_in[0];
  const float* W_ih = (const float*)d_in[1];
  const float* W_hh = (const float*)d_in[2];
  const float* b_ih = (const float*)d_in[3];
  const float* b_hh = (const float*)d_in[4];
  const float* fc_w = (const float*)d_in[5];
  const float* fc_b = (const float*)d_in[6];
  float* out = (float*)d_out;

  const int B = in_sizes[0] / (T_LEN * 8);  // 2048
  lstm_split<<<dim3(B / R), dim3(256), 0, stream>>>(x, W_ih, W_hh, b_ih, b_hh,
                                                    fc_w, fc_b, out);
}

// Round 14
// 394.448 us; speedup vs baseline: 1.0894x; 1.0635x over previous
//
#include <hip/hip_runtime.h>

// LSTM (B=2048, T=1024, I=8, H=64) + sigmoid(FC), bf16 MFMA, in-register
// activations, duplicate-column split, 2 blocks/CU — ANTI-PHASE + WEIGHT-
// FOLDED EXP SCALES + FUSED RCP + SETPRIO-SHARPENED MFMA PHASE.
//
// Machine model (locked r0-r13): per step each block runs an MFMA phase then
// a VALU act phase. A ONE-TIME s_sleep(7) stagger for half the blocks seeds
// MFMA/VALU anti-phase between the two co-resident blocks (verified r8/r11:
// MfmaUtil+VALUBusy up to 112.5%); the equilibrium self-sustains.
// DO NOT REMOVE THE STAGGER.
//
// Edit-category evidence:
//   LOCK-FATAL (phase-structure edits): r9 mid-step MFMA move (sum 90%,
//     462us); r10 ds_read hoist into act phase (sum 99%, 425us).
//   LOCK-SAFE (act-internal constants-only): r12 exp-scale fold (-10us);
//     r13 rcp fusion (flat — act issue count no longer binding).
// => memory ops, MFMA order (x->h0->h1), barrier placement are r8-identical.
//
// r14: T5 s_setprio — wrap the 12-MFMA cluster in setprio(1)/setprio(0).
// In the anti-phased state the SIMD hosts one MFMA-phase wave and one
// act-phase wave (role diversity = T5's prerequisite); the priority hint
// lets the MFMA-phase wave win issue arbitration at phase entry instead of
// round-robining against the partner's long VALU chain. Zero instructions
// moved; cluster boundary == existing phase boundary.
//
// Verified keeps: HP=80 (r0's 40 aliased h rows — correctness), weights
// pre-scaled (i,f,o rows x -log2e; g rows x +2log2e; c tracked pre-scaled),
// raw v_exp_f32 (NOT exp2f — slow ocml, r2), fused rcp forms, manual f2bf
// init, v_cvt_pk_bf16_f32 h-store, plain __syncthreads, full unroll on tt.

namespace {
constexpr int T_LEN = 1024;
constexpr int R     = 4;    // batch rows per block
constexpr int TS    = 32;   // timesteps of x per staged chunk
constexpr int HP    = 80;   // h_lds row stride in shorts (160 B, 16B-aligned)
constexpr float L2E = 1.4426950408889634f;

typedef __attribute__((ext_vector_type(8))) short  short8v;
typedef __attribute__((ext_vector_type(4))) float  float4v;
typedef unsigned short u16;
typedef unsigned long long u64;
typedef unsigned int u32;

__device__ __forceinline__ float exp2_raw(float x) {  // raw v_exp_f32
#if __has_builtin(__builtin_amdgcn_exp2f)
  return __builtin_amdgcn_exp2f(x);
#else
  float r;
  asm("v_exp_f32 %0, %1" : "=v"(r) : "v"(x));
  return r;
#endif
}
// y already scaled by -log2e: sigmoid = rcp(1 + 2^y). No input mul.
__device__ __forceinline__ float fsig_p(float y) {
  return __builtin_amdgcn_rcpf(1.f + exp2_raw(y));
}
__device__ __forceinline__ u16 f2bf(float f) {  // RNE (init-time only)
  u32 u = __float_as_uint(f);
  u32 r = ((u >> 16) & 1u) + 0x7fffu;
  return (u16)((u + r) >> 16);
}
__device__ __forceinline__ u16 cvt_bf16(float f) {  // 1 VALU op, RNE
  u32 d;
  asm("v_cvt_pk_bf16_f32 %0, %1, %2" : "=v"(d) : "v"(f), "v"(f));
  return (u16)d;
}

__global__ __launch_bounds__(256, 2) void lstm_split(
    const float* __restrict__ x,     // [B, T, 8]
    const float* __restrict__ W_ih,  // [256, 8]
    const float* __restrict__ W_hh,  // [256, 64]
    const float* __restrict__ b_ih,  // [256]
    const float* __restrict__ b_hh,  // [256]
    const float* __restrict__ fc_w,  // [64]
    const float* __restrict__ fc_b,  // [1]
    float* __restrict__ out) {       // [B]
  __shared__ __align__(16) u16   x_lds[2][TS][R][32];  // 16 KB; full K-rows
  __shared__ __align__(16) u16   h_lds[2][R][HP];      // 2.5 KB
  __shared__ __align__(16) float hf[R][64];            // final h (fp32)

  const int tid  = threadIdx.x;
  const int lane = tid & 63;
  const int wv   = tid >> 6;       // wave 0..3
  const int g4   = lane >> 4;      // MFMA k-quad / C row-quad
  const int nib  = lane & 15;      // MFMA m/n coord
  const int row  = nib & 3;        // batch row (cols 4..15 duplicate 0..3)
  const int rsel = nib >> 2;       // which acc reg this thread activates
  const int jh   = 16 * wv + 4 * g4 + rsel;  // owned h index
  const int bBase = blockIdx.x * R;

  // ---- static A fragments: wave wv holds tiles {4g+wv}, g=0..3 (i,f,g,o) ----
  // A[m=16*(4g+wv)+nib][k=8*g4+j]; frag0 k=0..31 = [W_ih(8)|bias|0...],
  // frag1 = W_hh[:,0:32], frag2 = W_hh[:,32:64].
  // EXP-SCALE FOLD: rows of gates i,f,o (g!=2) x(-log2e); gate g x(+2log2e).
  short8v a0[4], a1[4], a2[4];
  for (int g = 0; g < 4; ++g) {
    const float sc = (g == 2) ? (2.f * L2E) : (-L2E);
    const int n = 64 * g + 16 * wv + nib;  // gate row
    short8v f0, f1, f2;
    for (int j = 0; j < 8; ++j) {
      const int k = 8 * g4 + j;
      float v0 = 0.f;
      if (k < 8) v0 = W_ih[n * 8 + k];
      else if (k == 8) v0 = b_ih[n] + b_hh[n];
      f0[j] = (short)f2bf(sc * v0);
      f1[j] = (short)f2bf(sc * W_hh[n * 64 + k]);
      f2[j] = (short)f2bf(sc * W_hh[n * 64 + 32 + k]);
    }
    a0[g] = f0; a1[g] = f1; a2[g] = f2;
  }

  // ---- LDS init: h0 = 0 (both bufs); x constant channels once per buf ----
  for (int i = tid; i < 2 * R * HP; i += 256) ((u16*)h_lds)[i] = 0;
  {  // 256 threads <-> 2 bufs x 32 tt x 4 rows
    const int buf = tid >> 7, rem = tid & 127, tt = rem >> 2, rr = rem & 3;
    u16* p = &x_lds[buf][tt][rr][0];
    p[8] = 0x3f80;  // bias channel = 1.0
    for (int chn = 9; chn < 32; ++chn) p[chn] = 0;
  }

  // ---- x staging: 1 float4/thread/chunk, double-buffered ----
  float4v xr;
  const int sr = tid >> 6, sm = tid & 63;          // src row, float4 idx
  const int stt = sm >> 1, sch = (sm & 1) * 4;     // dest tt, channel
  auto stage_load = [&](int chunk) {
    const float* src = x + ((size_t)bBase + sr) * (T_LEN * 8) +
                       (size_t)chunk * (TS * 8);
    xr = *(const float4v*)&src[sm * 4];
  };
  auto stage_write = [&](int buf) {
    u32 lo, hi;
    asm("v_cvt_pk_bf16_f32 %0, %1, %2" : "=v"(lo) : "v"(xr[0]), "v"(xr[1]));
    asm("v_cvt_pk_bf16_f32 %0, %1, %2" : "=v"(hi) : "v"(xr[2]), "v"(xr[3]));
    const u64 p = ((u64)hi << 32) | (u64)lo;
    *(u64*)&x_lds[buf][stt][sr][sch] = p;
  };

  stage_load(0);
  stage_write(0);
  __syncthreads();

  // ---- ANTI-PHASE SEED: one-time ~448cy stagger for half the blocks ----
  // Parity (blockIdx ^ blockIdx>>8)&1 splits co-resident pairs under both
  // plausible mappings: (i, i+256) XCD round-robin and (2i, 2i+1).
  if (((blockIdx.x ^ (blockIdx.x >> 8)) & 1) != 0)
    __builtin_amdgcn_s_sleep(7);  // 7*64 = 448 cycles, once

  // hoisted select masks for the cndmask tree
  const bool sel1 = (rsel & 1) != 0;
  const bool sel2 = (rsel & 2) != 0;
  float c = 0.f;  // pre-scaled cell state: c' = 2*log2e * c_true

  for (int ch = 0; ch < T_LEN / TS; ++ch) {
    const int xb = ch & 1;
    const bool more = (ch < T_LEN / TS - 1);
#pragma unroll
    for (int tt = 0; tt < TS; ++tt) {
      const int t = ch * TS + tt;
      const int hb = t & 1;  // == tt & 1 (TS even); compile-time under unroll
      if (tt == 0 && more) stage_load(ch + 1);  // reg loads; drain in stage_write

      // ---- B fragments (uniform b128 reads) ----
      const short8v fx  = *(const short8v*)&x_lds[xb][tt][row][8 * g4];
      const short8v fh0 = *(const short8v*)&h_lds[hb][row][8 * g4];
      const short8v fh1 = *(const short8v*)&h_lds[hb][row][32 + 8 * g4];

      // ---- 12 MFMAs: 4 gate-quads x (x | h-lo | h-hi) ----
      // T5: priority hint so the MFMA-phase wave wins issue arbitration
      // against the co-resident block's act-phase wave (role diversity).
      __builtin_amdgcn_s_setprio(1);
      float4v acc[4];
#pragma unroll
      for (int g = 0; g < 4; ++g)
        acc[g] = __builtin_amdgcn_mfma_f32_16x16x32_bf16(
            a0[g], fx, (float4v){0.f, 0.f, 0.f, 0.f}, 0, 0, 0);
#pragma unroll
      for (int g = 0; g < 4; ++g)
        acc[g] = __builtin_amdgcn_mfma_f32_16x16x32_bf16(a1[g], fh0, acc[g], 0, 0, 0);
#pragma unroll
      for (int g = 0; g < 4; ++g)
        acc[g] = __builtin_amdgcn_mfma_f32_16x16x32_bf16(a2[g], fh1, acc[g], 0, 0, 0);
      __builtin_amdgcn_s_setprio(0);

      // ---- pick this thread's element (reg-select tree) and activate ----
      // gsel arrives pre-scaled: i,f,o by -log2e; g by 2log2e.
      float gsel[4];
#pragma unroll
      for (int g = 0; g < 4; ++g) {
        const float x01 = sel1 ? acc[g][1] : acc[g][0];
        const float x23 = sel1 ? acc[g][3] : acc[g][2];
        gsel[g] = sel2 ? x23 : x01;
      }
      // I = e^-i, F = e^-f, G = e^{2g}, O = e^-o (scales folded in weights)
      const float I = exp2_raw(gsel[0]);
      const float F = exp2_raw(gsel[1]);
      const float G = exp2_raw(gsel[2]);
      const float O = exp2_raw(gsel[3]);
      // c' = sig(f)*c' + 2log2e*sig(i)*tanh(g)
      //    = rcp(1+F)*c' + [2log2e*(G-1)] * rcp((1+I)*(G+1))   (fused rcp)
      const float s   = __builtin_fmaf(2.f * L2E, G, -2.f * L2E);  // 2L2E(G-1)
      const float dIG = (1.f + I) * (G + 1.f);
      const float t2  = s * __builtin_amdgcn_rcpf(dIG);
      c = __builtin_fmaf(__builtin_amdgcn_rcpf(1.f + F), c, t2);
      // h = tanh(c)*sig(o) = (C-1) * rcp((C+1)*(1+O)), C = exp2(c') = e^{2c}
      const float C   = exp2_raw(c);
      const float dCO = (C + 1.f) * (1.f + O);
      const float h   = (C - 1.f) * __builtin_amdgcn_rcpf(dCO);
      h_lds[hb ^ 1][row][jh] = cvt_bf16(h);
      if (t == T_LEN - 1) hf[row][jh] = h;
      if (tt == TS - 1 && more) stage_write((ch + 1) & 1);
      __syncthreads();  // one barrier per step
    }
  }

  // ---- epilogue: out[b] = sigmoid(hT . fc_w + fc_b) ----
  if (tid < R) {
    float a = fc_b[0];
#pragma unroll
    for (int k = 0; k < 64; ++k) a += hf[tid][k] * fc_w[k];
    out[bBase + tid] = fsig_p(-L2E * a);  // unscaled input: explicit mul
  }
}
}  // namespace

extern "C" void kernel_launch(void* const* d_in, const int* in_sizes, int n_in,
                              void* d_out, int out_size, void* d_ws,
                              size_t ws_size, hipStream_t stream) {
  const float* x    = (const float*)d_in[0];
  const float* W_ih = (const float*)d_in[1];
  const float* W_hh = (const float*)d_in[2];
  const float* b_ih = (const float*)d_in[3];
  const float* b_hh = (const float*)d_in[4];
  const float* fc_w = (const float*)d_in[5];
  const float* fc_b = (const float*)d_in[6];
  float* out = (float*)d_out;

  const int B = in_sizes[0] / (T_LEN * 8);  // 2048
  lstm_split<<<dim3(B / R), dim3(256), 0, stream>>>(x, W_ih, W_hh, b_ih, b_hh,
                                                    fc_w, fc_b, out);
}

// Round 15
// 384.835 us; speedup vs baseline: 1.1166x; 1.0250x over previous
//
#include <hip/hip_runtime.h>

// LSTM (B=2048, T=1024, I=8, H=64) + sigmoid(FC), bf16 MFMA, in-register
// activations, duplicate-column split, 2 blocks/CU — ANTI-PHASE + WEIGHT-
// FOLDED EXP SCALES + FUSED RCP + SETPRIO OVER READ-HEAD AND MFMA PHASE.
//
// Machine model (locked r0-r14): per step each block runs {ds_read head ->
// MFMA phase} then {VALU act phase}. A ONE-TIME s_sleep(7) stagger for half
// the blocks seeds MFMA/VALU anti-phase between the two co-resident blocks;
// verified r8/r11 (sum MfmaUtil+VALUBusy 112.5%). r14 added T5 setprio(1)
// around the MFMA cluster: 378 -> 355us, sum 113.4%. DO NOT REMOVE THE
// STAGGER OR THE SETPRIO.
//
// Edit-category evidence:
//   LOCK-FATAL (phase-structure edits): r9 mid-step MFMA move (sum 90%);
//     r10 ds_read hoist into act phase (sum 99%).
//   LOCK-SAFE: r12 constants-only act trims (-10us); r14 setprio (T5, -23us).
// => memory ops, MFMA order (x->h0->h1), barrier placement are r8-identical.
//
// r15: single-variable extension of the r14 window — setprio(1) now starts
// BEFORE the three B-fragment ds_reads (reads do not move; only the issuing
// wave's priority changes), so the just-barrier-exited wave gets its
// ds_reads issued without round-robining against the partner block's act
// wave. Window still ends after the 12th MFMA.
//
// Verified keeps: HP=80 (r0's 40 aliased h rows — correctness), weights
// pre-scaled (i,f,o rows x -log2e; g rows x +2log2e; c tracked pre-scaled),
// raw v_exp_f32 (NOT exp2f — slow ocml, r2), fused rcp forms, manual f2bf
// init, v_cvt_pk_bf16_f32 h-store, plain __syncthreads, full unroll on tt.

namespace {
constexpr int T_LEN = 1024;
constexpr int R     = 4;    // batch rows per block
constexpr int TS    = 32;   // timesteps of x per staged chunk
constexpr int HP    = 80;   // h_lds row stride in shorts (160 B, 16B-aligned)
constexpr float L2E = 1.4426950408889634f;

typedef __attribute__((ext_vector_type(8))) short  short8v;
typedef __attribute__((ext_vector_type(4))) float  float4v;
typedef unsigned short u16;
typedef unsigned long long u64;
typedef unsigned int u32;

__device__ __forceinline__ float exp2_raw(float x) {  // raw v_exp_f32
#if __has_builtin(__builtin_amdgcn_exp2f)
  return __builtin_amdgcn_exp2f(x);
#else
  float r;
  asm("v_exp_f32 %0, %1" : "=v"(r) : "v"(x));
  return r;
#endif
}
// y already scaled by -log2e: sigmoid = rcp(1 + 2^y). No input mul.
__device__ __forceinline__ float fsig_p(float y) {
  return __builtin_amdgcn_rcpf(1.f + exp2_raw(y));
}
__device__ __forceinline__ u16 f2bf(float f) {  // RNE (init-time only)
  u32 u = __float_as_uint(f);
  u32 r = ((u >> 16) & 1u) + 0x7fffu;
  return (u16)((u + r) >> 16);
}
__device__ __forceinline__ u16 cvt_bf16(float f) {  // 1 VALU op, RNE
  u32 d;
  asm("v_cvt_pk_bf16_f32 %0, %1, %2" : "=v"(d) : "v"(f), "v"(f));
  return (u16)d;
}

__global__ __launch_bounds__(256, 2) void lstm_split(
    const float* __restrict__ x,     // [B, T, 8]
    const float* __restrict__ W_ih,  // [256, 8]
    const float* __restrict__ W_hh,  // [256, 64]
    const float* __restrict__ b_ih,  // [256]
    const float* __restrict__ b_hh,  // [256]
    const float* __restrict__ fc_w,  // [64]
    const float* __restrict__ fc_b,  // [1]
    float* __restrict__ out) {       // [B]
  __shared__ __align__(16) u16   x_lds[2][TS][R][32];  // 16 KB; full K-rows
  __shared__ __align__(16) u16   h_lds[2][R][HP];      // 2.5 KB
  __shared__ __align__(16) float hf[R][64];            // final h (fp32)

  const int tid  = threadIdx.x;
  const int lane = tid & 63;
  const int wv   = tid >> 6;       // wave 0..3
  const int g4   = lane >> 4;      // MFMA k-quad / C row-quad
  const int nib  = lane & 15;      // MFMA m/n coord
  const int row  = nib & 3;        // batch row (cols 4..15 duplicate 0..3)
  const int rsel = nib >> 2;       // which acc reg this thread activates
  const int jh   = 16 * wv + 4 * g4 + rsel;  // owned h index
  const int bBase = blockIdx.x * R;

  // ---- static A fragments: wave wv holds tiles {4g+wv}, g=0..3 (i,f,g,o) ----
  // A[m=16*(4g+wv)+nib][k=8*g4+j]; frag0 k=0..31 = [W_ih(8)|bias|0...],
  // frag1 = W_hh[:,0:32], frag2 = W_hh[:,32:64].
  // EXP-SCALE FOLD: rows of gates i,f,o (g!=2) x(-log2e); gate g x(+2log2e).
  short8v a0[4], a1[4], a2[4];
  for (int g = 0; g < 4; ++g) {
    const float sc = (g == 2) ? (2.f * L2E) : (-L2E);
    const int n = 64 * g + 16 * wv + nib;  // gate row
    short8v f0, f1, f2;
    for (int j = 0; j < 8; ++j) {
      const int k = 8 * g4 + j;
      float v0 = 0.f;
      if (k < 8) v0 = W_ih[n * 8 + k];
      else if (k == 8) v0 = b_ih[n] + b_hh[n];
      f0[j] = (short)f2bf(sc * v0);
      f1[j] = (short)f2bf(sc * W_hh[n * 64 + k]);
      f2[j] = (short)f2bf(sc * W_hh[n * 64 + 32 + k]);
    }
    a0[g] = f0; a1[g] = f1; a2[g] = f2;
  }

  // ---- LDS init: h0 = 0 (both bufs); x constant channels once per buf ----
  for (int i = tid; i < 2 * R * HP; i += 256) ((u16*)h_lds)[i] = 0;
  {  // 256 threads <-> 2 bufs x 32 tt x 4 rows
    const int buf = tid >> 7, rem = tid & 127, tt = rem >> 2, rr = rem & 3;
    u16* p = &x_lds[buf][tt][rr][0];
    p[8] = 0x3f80;  // bias channel = 1.0
    for (int chn = 9; chn < 32; ++chn) p[chn] = 0;
  }

  // ---- x staging: 1 float4/thread/chunk, double-buffered ----
  float4v xr;
  const int sr = tid >> 6, sm = tid & 63;          // src row, float4 idx
  const int stt = sm >> 1, sch = (sm & 1) * 4;     // dest tt, channel
  auto stage_load = [&](int chunk) {
    const float* src = x + ((size_t)bBase + sr) * (T_LEN * 8) +
                       (size_t)chunk * (TS * 8);
    xr = *(const float4v*)&src[sm * 4];
  };
  auto stage_write = [&](int buf) {
    u32 lo, hi;
    asm("v_cvt_pk_bf16_f32 %0, %1, %2" : "=v"(lo) : "v"(xr[0]), "v"(xr[1]));
    asm("v_cvt_pk_bf16_f32 %0, %1, %2" : "=v"(hi) : "v"(xr[2]), "v"(xr[3]));
    const u64 p = ((u64)hi << 32) | (u64)lo;
    *(u64*)&x_lds[buf][stt][sr][sch] = p;
  };

  stage_load(0);
  stage_write(0);
  __syncthreads();

  // ---- ANTI-PHASE SEED: one-time ~448cy stagger for half the blocks ----
  // Parity (blockIdx ^ blockIdx>>8)&1 splits co-resident pairs under both
  // plausible mappings: (i, i+256) XCD round-robin and (2i, 2i+1).
  if (((blockIdx.x ^ (blockIdx.x >> 8)) & 1) != 0)
    __builtin_amdgcn_s_sleep(7);  // 7*64 = 448 cycles, once

  // hoisted select masks for the cndmask tree
  const bool sel1 = (rsel & 1) != 0;
  const bool sel2 = (rsel & 2) != 0;
  float c = 0.f;  // pre-scaled cell state: c' = 2*log2e * c_true

  for (int ch = 0; ch < T_LEN / TS; ++ch) {
    const int xb = ch & 1;
    const bool more = (ch < T_LEN / TS - 1);
#pragma unroll
    for (int tt = 0; tt < TS; ++tt) {
      const int t = ch * TS + tt;
      const int hb = t & 1;  // == tt & 1 (TS even); compile-time under unroll
      if (tt == 0 && more) stage_load(ch + 1);  // reg loads; drain in stage_write

      // ---- priority window opens BEFORE the read head (r15): the
      //      just-barrier-exited wave issues its ds_reads + MFMAs without
      //      round-robining against the partner block's act-phase wave ----
      __builtin_amdgcn_s_setprio(1);

      // ---- B fragments (uniform b128 reads; positions unchanged) ----
      const short8v fx  = *(const short8v*)&x_lds[xb][tt][row][8 * g4];
      const short8v fh0 = *(const short8v*)&h_lds[hb][row][8 * g4];
      const short8v fh1 = *(const short8v*)&h_lds[hb][row][32 + 8 * g4];

      // ---- 12 MFMAs: 4 gate-quads x (x | h-lo | h-hi) ----
      float4v acc[4];
#pragma unroll
      for (int g = 0; g < 4; ++g)
        acc[g] = __builtin_amdgcn_mfma_f32_16x16x32_bf16(
            a0[g], fx, (float4v){0.f, 0.f, 0.f, 0.f}, 0, 0, 0);
#pragma unroll
      for (int g = 0; g < 4; ++g)
        acc[g] = __builtin_amdgcn_mfma_f32_16x16x32_bf16(a1[g], fh0, acc[g], 0, 0, 0);
#pragma unroll
      for (int g = 0; g < 4; ++g)
        acc[g] = __builtin_amdgcn_mfma_f32_16x16x32_bf16(a2[g], fh1, acc[g], 0, 0, 0);
      __builtin_amdgcn_s_setprio(0);

      // ---- pick this thread's element (reg-select tree) and activate ----
      // gsel arrives pre-scaled: i,f,o by -log2e; g by 2log2e.
      float gsel[4];
#pragma unroll
      for (int g = 0; g < 4; ++g) {
        const float x01 = sel1 ? acc[g][1] : acc[g][0];
        const float x23 = sel1 ? acc[g][3] : acc[g][2];
        gsel[g] = sel2 ? x23 : x01;
      }
      // I = e^-i, F = e^-f, G = e^{2g}, O = e^-o (scales folded in weights)
      const float I = exp2_raw(gsel[0]);
      const float F = exp2_raw(gsel[1]);
      const float G = exp2_raw(gsel[2]);
      const float O = exp2_raw(gsel[3]);
      // c' = sig(f)*c' + 2log2e*sig(i)*tanh(g)
      //    = rcp(1+F)*c' + [2log2e*(G-1)] * rcp((1+I)*(G+1))   (fused rcp)
      const float s   = __builtin_fmaf(2.f * L2E, G, -2.f * L2E);  // 2L2E(G-1)
      const float dIG = (1.f + I) * (G + 1.f);
      const float t2  = s * __builtin_amdgcn_rcpf(dIG);
      c = __builtin_fmaf(__builtin_amdgcn_rcpf(1.f + F), c, t2);
      // h = tanh(c)*sig(o) = (C-1) * rcp((C+1)*(1+O)), C = exp2(c') = e^{2c}
      const float C   = exp2_raw(c);
      const float dCO = (C + 1.f) * (1.f + O);
      const float h   = (C - 1.f) * __builtin_amdgcn_rcpf(dCO);
      h_lds[hb ^ 1][row][jh] = cvt_bf16(h);
      if (t == T_LEN - 1) hf[row][jh] = h;
      if (tt == TS - 1 && more) stage_write((ch + 1) & 1);
      __syncthreads();  // one barrier per step
    }
  }

  // ---- epilogue: out[b] = sigmoid(hT . fc_w + fc_b) ----
  if (tid < R) {
    float a = fc_b[0];
#pragma unroll
    for (int k = 0; k < 64; ++k) a += hf[tid][k] * fc_w[k];
    out[bBase + tid] = fsig_p(-L2E * a);  // unscaled input: explicit mul
  }
}
}  // namespace

extern "C" void kernel_launch(void* const* d_in, const int* in_sizes, int n_in,
                              void* d_out, int out_size, void* d_ws,
                              size_t ws_size, hipStream_t stream) {
  const float* x    = (const float*)d_in[0];
  const float* W_ih = (const float*)d_in[1];
  const float* W_hh = (const float*)d_in[2];
  const float* b_ih = (const float*)d_in[3];
  const float* b_hh = (const float*)d_in[4];
  const float* fc_w = (const float*)d_in[5];
  const float* fc_b = (const float*)d_in[6];
  float* out = (float*)d_out;

  const int B = in_sizes[0] / (T_LEN * 8);  // 2048
  lstm_split<<<dim3(B / R), dim3(256), 0, stream>>>(x, W_ih, W_hh, b_ih, b_hh,
                                                    fc_w, fc_b, out);
}